// Round 5
// baseline (518.373 us; speedup 1.0000x reference)
//
#include <hip/hip_runtime.h>
#include <hip/hip_bf16.h>

#define T_TOK 8192
#define HDIM 1024
#define FDIM 2048
#define NEXP 8
#define NASSIGN (T_TOK * 2)
#define ROWCAP (NASSIGN + 128)  // packed rows + tail-tile slack
#define NHB 64                  // hist/scatter blocks
#define MT_MAX (T_TOK / 128)    // worst-case m-tiles per expert

typedef __bf16 bf16;
typedef __bf16 bf16x4 __attribute__((ext_vector_type(4)));
typedef __bf16 bf16x8 __attribute__((ext_vector_type(8)));
typedef float f32x4 __attribute__((ext_vector_type(4)));

// async global->LDS, 16B per lane; LDS dest = wave-uniform base + lane*16
__device__ __forceinline__ void gload_lds16(const void* g, void* l) {
    __builtin_amdgcn_global_load_lds(
        (const __attribute__((address_space(1))) void*)(uintptr_t)g,
        (__attribute__((address_space(3))) void*)(uintptr_t)l,
        16, 0, 0);
}

// ---------------- transpose + fp32->bf16: in [E][R][C] fp32 -> out [E][C][R] bf16 ----------------
__global__ __launch_bounds__(256) void transpose_to_bf16(
    const float* __restrict__ in, bf16* __restrict__ out, int R, int C) {
    __shared__ float tile[64][68];
    int e = blockIdx.z;
    const float* inp = in + (size_t)e * R * C;
    bf16* outp = out + (size_t)e * R * C;
    int c0 = blockIdx.x * 64, r0 = blockIdx.y * 64;
    int tid = threadIdx.x;
    int tx = tid & 15, ty = tid >> 4;
#pragma unroll
    for (int i = 0; i < 4; i++) {
        int row = ty + i * 16;
        float4 v = *(const float4*)&inp[(size_t)(r0 + row) * C + c0 + tx * 4];
        *(float4*)&tile[row][tx * 4] = v;
    }
    __syncthreads();
#pragma unroll
    for (int i = 0; i < 2; i++) {
        int idx = tid + i * 256;
        int c = idx >> 3, seg = idx & 7;
        bf16x8 v;
#pragma unroll
        for (int j = 0; j < 8; j++) v[j] = (bf16)tile[seg * 8 + j][c];
        *(bf16x8*)&outp[(size_t)(c0 + c) * R + r0 + seg * 8] = v;
    }
}

// ---------------- phase A: per-token top-2 + gates (NO atomics) ----------------
__global__ __launch_bounds__(256) void router_kernel(
    const float* __restrict__ x, const float* __restrict__ rw,
    const float* __restrict__ rb, int* __restrict__ expert_pair,
    float2* __restrict__ gate_pair) {
    __shared__ float rwT[NEXP][HDIM];
    __shared__ float rbs[NEXP];
    int tid = threadIdx.x;
    for (int i = tid; i < HDIM * NEXP / 4; i += 256) {
        float4 v = ((const float4*)rw)[i];
        int h = i >> 1, e0 = (i & 1) * 4;
        rwT[e0 + 0][h] = v.x;
        rwT[e0 + 1][h] = v.y;
        rwT[e0 + 2][h] = v.z;
        rwT[e0 + 3][h] = v.w;
    }
    if (tid < NEXP) rbs[tid] = rb[tid];
    __syncthreads();
    int wave = tid >> 6, lane = tid & 63;
    int tbase = blockIdx.x * 32 + wave * 8;

    for (int tk = 0; tk < 8; tk++) {
        int t = tbase + tk;
        const float4* xt = (const float4*)(x + (size_t)t * HDIM);
        float p[NEXP];
#pragma unroll
        for (int e = 0; e < NEXP; e++) p[e] = 0.f;
#pragma unroll
        for (int it = 0; it < 4; it++) {
            float4 v = xt[it * 64 + lane];
            int h = (it * 64 + lane) * 4;
#pragma unroll
            for (int e = 0; e < NEXP; e++) {
                float4 wv = *(const float4*)&rwT[e][h];
                p[e] += v.x * wv.x + v.y * wv.y + v.z * wv.z + v.w * wv.w;
            }
        }
#pragma unroll
        for (int off = 32; off >= 1; off >>= 1) {
#pragma unroll
            for (int e = 0; e < NEXP; e++) p[e] += __shfl_xor(p[e], off, 64);
        }
        if (lane == 0) {
            float lg[NEXP];
#pragma unroll
            for (int e = 0; e < NEXP; e++) lg[e] = p[e] + rbs[e];
            int e0 = 0;
#pragma unroll
            for (int e = 1; e < NEXP; e++)
                if (lg[e] > lg[e0]) e0 = e;
            int e1 = -1;
#pragma unroll
            for (int e = 0; e < NEXP; e++) {
                if (e == e0) continue;
                if (e1 < 0 || lg[e] > lg[e1]) e1 = e;
            }
            float z = expf(lg[e1] - lg[e0]);
            expert_pair[t] = e0 | (e1 << 16);
            gate_pair[t] = make_float2(1.f / (1.f + z), z / (1.f + z));
        }
    }
}

// ---------------- phase B: per-block expert histogram via ballots ----------------
__global__ __launch_bounds__(256) void hist_kernel(
    const int* __restrict__ expert_pair, int* __restrict__ hist) {
    int tid = threadIdx.x;
    int wave = tid >> 6, lane = tid & 63;
    int a = blockIdx.x * 256 + tid;
    int t = a >> 1, j = a & 1;
    int e = (expert_pair[t] >> (16 * j)) & 0xffff;
    __shared__ int wcnt[4][NEXP];
#pragma unroll
    for (int ee = 0; ee < NEXP; ee++) {
        unsigned long long m = __ballot(e == ee);
        if (lane == 0) wcnt[wave][ee] = __popcll(m);
    }
    __syncthreads();
    if (tid < NEXP)
        hist[blockIdx.x * NEXP + tid] =
            wcnt[0][tid] + wcnt[1][tid] + wcnt[2][tid] + wcnt[3][tid];
}

// ---------------- phase C: scan -> cnt, offs, per-block starts ----------------
__global__ __launch_bounds__(256) void scan_kernel(
    const int* __restrict__ hist, int* __restrict__ start,
    int* __restrict__ cnt, int* __restrict__ offs) {
    __shared__ int h[NHB * NEXP];
    __shared__ int tot[NEXP];
    __shared__ int offsh[NEXP];
    int tid = threadIdx.x;
    for (int i = tid; i < NHB * NEXP; i += 256) h[i] = hist[i];
    __syncthreads();
    if (tid < NEXP) {
        int s = 0;
        for (int b = 0; b < NHB; b++) s += h[b * NEXP + tid];
        tot[tid] = s;
        cnt[tid] = s;
    }
    __syncthreads();
    if (tid == 0) {
        int o = 0;
        for (int e = 0; e < NEXP; e++) {
            offsh[e] = o;
            offs[e] = o;
            o += tot[e];
        }
    }
    __syncthreads();
    if (tid < NEXP) {
        int run = offsh[tid];
        for (int b = 0; b < NHB; b++) {
            start[b * NEXP + tid] = run;
            run += h[b * NEXP + tid];
        }
    }
}

// ---------------- phase D: deterministic scatter via ballot ranks ----------------
__global__ __launch_bounds__(256) void scatter_kernel(
    const int* __restrict__ expert_pair, const float2* __restrict__ gate_pair,
    const int* __restrict__ start, int* __restrict__ perm,
    float* __restrict__ gatebuf, int* __restrict__ rowbuf) {
    int tid = threadIdx.x;
    int wave = tid >> 6, lane = tid & 63;
    int a = blockIdx.x * 256 + tid;
    int t = a >> 1, j = a & 1;
    int e = (expert_pair[t] >> (16 * j)) & 0xffff;
    float2 gp = gate_pair[t];
    float g = j ? gp.y : gp.x;
    __shared__ int wcnt[4][NEXP];
    int rankw = 0;
    unsigned long long below = (1ull << lane) - 1ull;
#pragma unroll
    for (int ee = 0; ee < NEXP; ee++) {
        unsigned long long m = __ballot(e == ee);
        if (lane == 0) wcnt[wave][ee] = __popcll(m);
        if (ee == e) rankw = __popcll(m & below);
    }
    __syncthreads();
    int cross = 0;
    for (int w = 0; w < wave; w++) cross += wcnt[w][e];
    int pos = start[blockIdx.x * NEXP + e] + cross + rankw;
    perm[pos] = t;
    gatebuf[pos] = g;
    rowbuf[a] = pos;
}

// ---------------- pack: gather x rows into packed order, fp32 -> bf16 ----------------
__global__ __launch_bounds__(256) void pack_kernel(
    const float* __restrict__ x, const int* __restrict__ perm,
    bf16* __restrict__ xg) {
    int r0 = blockIdx.x * 16;
    int wave = threadIdx.x >> 6, lane = threadIdx.x & 63;
#pragma unroll
    for (int i = 0; i < 4; i++) {
        int row = r0 + wave * 4 + i;
        int tok = perm[row];
        const float* src = x + (size_t)tok * HDIM;
        bf16* dst = xg + (size_t)row * HDIM;
#pragma unroll
        for (int it = 0; it < 4; it++) {
            int c = (it * 64 + lane) * 4;
            float4 v = *(const float4*)&src[c];
            bf16x4 b = {(bf16)v.x, (bf16)v.y, (bf16)v.z, (bf16)v.w};
            *(bf16x4*)&dst[c] = b;
        }
    }
}

// ---------------- grouped GEMM: BK=64, expert<->XCD swizzle, XOR-swizzled LDS ----------------
// 1D grid: lin&7 = expert (XCD affinity), r = lin>>3, nt = r % (N/128), mt = r / (N/128).
template <int K, int N, bool RELU, bool GATE>
__global__ __launch_bounds__(256) void moe_gemm(
    const bf16* __restrict__ A, const bf16* __restrict__ B,
    const float* __restrict__ bias, const float* __restrict__ gates,
    bf16* __restrict__ out, const int* __restrict__ cnt,
    const int* __restrict__ offs) {
    constexpr int NT = N / 128;
    int lin = blockIdx.x;
    int e = lin & 7;
    int r = lin >> 3;
    int nt = r % NT, mt = r / NT;
    int n_cnt = cnt[e];
    int m0 = mt * 128;
    if (m0 >= n_cnt) return;
    int n0 = nt * 128;

    __shared__ bf16 As[128 * 64];
    __shared__ bf16 Bs[128 * 64];

    int tid = threadIdx.x;
    int lane = tid & 63;
    int wave = tid >> 6;
    int wm = (wave & 1) * 64, wn = (wave >> 1) * 64;
    int quad = lane >> 4;
    int l16 = lane & 15;

    int off_e = offs[e];
    const bf16* Ae = A + (size_t)off_e * K;
    const bf16* Be = B + (size_t)e * N * K;

    // staging: each call covers 8 rows x 64 k. lane -> row (lane>>3), phys chunk (lane&7).
    // XOR swizzle: logical chunk c = pc ^ (row&7); row&7 == lane>>3 here.
    int srow8 = lane >> 3;
    int ccol = ((lane & 7) ^ srow8) * 8;
    const bf16* ag[4];
    const bf16* bg[4];
    bf16* asl[4];
    bf16* bsl[4];
#pragma unroll
    for (int i = 0; i < 4; i++) {
        int rowb = wave * 32 + i * 8;
        ag[i] = Ae + (size_t)(m0 + rowb + srow8) * K + ccol;
        bg[i] = Be + (size_t)(n0 + rowb + srow8) * K + ccol;
        asl[i] = &As[rowb * 64];
        bsl[i] = &Bs[rowb * 64];
    }
    // ds_read: logical chunk for k-step s = 4s+quad; phys = (4s+quad) ^ (l16&7)
    int rchunk = l16 & 7;

    f32x4 acc[4][4];
#pragma unroll
    for (int i = 0; i < 4; i++)
#pragma unroll
        for (int j = 0; j < 4; j++) acc[i][j] = f32x4{0.f, 0.f, 0.f, 0.f};

#pragma unroll 1
    for (int k0 = 0; k0 < K; k0 += 64) {
#pragma unroll
        for (int i = 0; i < 4; i++) {
            gload_lds16(ag[i] + k0, asl[i]);
            gload_lds16(bg[i] + k0, bsl[i]);
        }
        __syncthreads();
#pragma unroll
        for (int s = 0; s < 2; s++) {
            bf16x8 af[4], bfr[4];
            int chnk = ((4 * s + quad) ^ rchunk) * 8;
#pragma unroll
            for (int i = 0; i < 4; i++)
                af[i] = *(const bf16x8*)&As[(wm + i * 16 + l16) * 64 + chnk];
#pragma unroll
            for (int j = 0; j < 4; j++)
                bfr[j] = *(const bf16x8*)&Bs[(wn + j * 16 + l16) * 64 + chnk];
#pragma unroll
            for (int i = 0; i < 4; i++)
#pragma unroll
                for (int j = 0; j < 4; j++)
                    acc[i][j] = __builtin_amdgcn_mfma_f32_16x16x32_bf16(af[i], bfr[j], acc[i][j], 0, 0, 0);
        }
        __syncthreads();
    }

#pragma unroll
    for (int i = 0; i < 4; i++)
#pragma unroll
        for (int j = 0; j < 4; j++)
#pragma unroll
            for (int rr = 0; rr < 4; rr++) {
                int m = m0 + wm + i * 16 + quad * 4 + rr;
                if (m < n_cnt) {
                    int n = n0 + wn + j * 16 + l16;
                    float v = acc[i][j][rr] + bias[e * N + n];
                    if (RELU) v = v > 0.f ? v : 0.f;
                    if (GATE) v *= gates[off_e + m];
                    out[(size_t)(off_e + m) * N + n] = (bf16)v;
                }
            }
}

// ---------------- combine ----------------
__global__ __launch_bounds__(256) void combine_kernel(
    const bf16* __restrict__ eout, const int* __restrict__ rowbuf,
    float* __restrict__ out) {
    int t = blockIdx.x;
    int r0 = rowbuf[2 * t], r1 = rowbuf[2 * t + 1];
    const bf16* p0 = eout + (size_t)r0 * HDIM;
    const bf16* p1 = eout + (size_t)r1 * HDIM;
    float* o = out + (size_t)t * HDIM;
    int n = threadIdx.x * 4;
    bf16x4 a = *(const bf16x4*)&p0[n];
    bf16x4 b = *(const bf16x4*)&p1[n];
    float4 v = {(float)a[0] + (float)b[0], (float)a[1] + (float)b[1],
                (float)a[2] + (float)b[2], (float)a[3] + (float)b[3]};
    *(float4*)&o[n] = v;
}

extern "C" void kernel_launch(void* const* d_in, const int* in_sizes, int n_in,
                              void* d_out, int out_size, void* d_ws, size_t ws_size,
                              hipStream_t stream) {
    const float* x = (const float*)d_in[0];
    const float* rw = (const float*)d_in[1];
    const float* rb = (const float*)d_in[2];
    const float* w1 = (const float*)d_in[3];
    const float* b1 = (const float*)d_in[4];
    const float* w2 = (const float*)d_in[5];
    const float* b2 = (const float*)d_in[6];
    float* out = (float*)d_out;

    char* ws = (char*)d_ws;
    size_t o = 0;
    auto alloc = [&](size_t bytes) {
        char* p = ws + o;
        o += (bytes + 255) & ~(size_t)255;
        return p;
    };
    bf16* w1t = (bf16*)alloc((size_t)NEXP * FDIM * HDIM * 2);
    bf16* w2t = (bf16*)alloc((size_t)NEXP * HDIM * FDIM * 2);
    bf16* hbuf = (bf16*)alloc((size_t)ROWCAP * FDIM * 2);
    bf16* xg = (bf16*)alloc((size_t)ROWCAP * HDIM * 2);  // aliased: xg (gemm1 A) then eout (gemm2 out)
    bf16* eout = xg;
    int* expert_pair = (int*)alloc((size_t)T_TOK * 4);
    float2* gate_pair = (float2*)alloc((size_t)T_TOK * 8);
    int* hist = (int*)alloc((size_t)NHB * NEXP * 4);
    int* start = (int*)alloc((size_t)NHB * NEXP * 4);
    int* perm = (int*)alloc((size_t)NASSIGN * 4);
    float* gatebuf = (float*)alloc((size_t)NASSIGN * 4);
    int* rowbuf = (int*)alloc((size_t)NASSIGN * 4);
    int* cnt = (int*)alloc(256);
    int* offs = (int*)alloc(256);

    transpose_to_bf16<<<dim3(FDIM / 64, HDIM / 64, NEXP), 256, 0, stream>>>(w1, w1t, HDIM, FDIM);
    transpose_to_bf16<<<dim3(HDIM / 64, FDIM / 64, NEXP), 256, 0, stream>>>(w2, w2t, FDIM, HDIM);
    router_kernel<<<T_TOK / 32, 256, 0, stream>>>(x, rw, rb, expert_pair, gate_pair);
    hist_kernel<<<NHB, 256, 0, stream>>>(expert_pair, hist);
    scan_kernel<<<1, 256, 0, stream>>>(hist, start, cnt, offs);
    scatter_kernel<<<NHB, 256, 0, stream>>>(expert_pair, gate_pair, start, perm, gatebuf, rowbuf);
    pack_kernel<<<NASSIGN / 16, 256, 0, stream>>>(x, perm, xg);
    moe_gemm<HDIM, FDIM, true, false><<<NEXP * (FDIM / 128) * MT_MAX, 256, 0, stream>>>(
        xg, w1t, b1, nullptr, hbuf, cnt, offs);
    moe_gemm<FDIM, HDIM, false, true><<<NEXP * (HDIM / 128) * MT_MAX, 256, 0, stream>>>(
        hbuf, w2t, b2, gatebuf, eout, cnt, offs);
    combine_kernel<<<T_TOK, 256, 0, stream>>>(eout, rowbuf, out);
}